// Round 16
// baseline (71.783 us; speedup 1.0000x reference)
//
#include <hip/hip_runtime.h>

#define IMG_H 1080
#define IMG_W 1920
#define CH 3
#define TW 128          // tile cols (= 64 lanes x 2)
#define TH 8            // tile output rows
#define INR 10          // staged input rows (TH + 2 halo)
#define NPL 6           // planes: pred c0..2, gt c0..2
#define NPR 60          // plane-rows = NPL * INR

typedef float f32x2 __attribute__((ext_vector_type(2)));

#if __has_builtin(__builtin_elementwise_fma)
#define FMA2(a, b, c) __builtin_elementwise_fma((a), (b), (c))
#else
#define FMA2(a, b, c) ((a) * (b) + (c))
#endif

// DPP wave shifts: single VALU op, no DS pipe (validated R14).
__device__ __forceinline__ float dpp_up1(float x) {
    int i = __float_as_int(x);
    return __int_as_float(__builtin_amdgcn_update_dpp(i, i, 0x138, 0xF, 0xF, false));
}
__device__ __forceinline__ float dpp_dn1(float x) {
    int i = __float_as_int(x);
    return __int_as_float(__builtin_amdgcn_update_dpp(i, i, 0x130, 0xF, 0xF, false));
}

// fire-and-forget global->LDS, 16 B per lane; LDS dest = base + lane*16
__device__ __forceinline__ void gload16(const float* g, float* l) {
    __builtin_amdgcn_global_load_lds(
        (const __attribute__((address_space(1))) void*)g,
        (__attribute__((address_space(3))) void*)l,
        16, 0, 0);
}

__device__ __forceinline__ int reflect_row(int r) {
    return (r < 0) ? 1 : ((r >= IMG_H) ? 2 * IMG_H - 2 - r : r);
}

__global__ __launch_bounds__(256)
void dssim_l1_kernel(const float* __restrict__ pred,
                     const float* __restrict__ gt,
                     float* __restrict__ out) {
    constexpr float K1 = 81.0f * 0.0001f;        // 81*C1
    constexpr float K2 = 81.0f * 0.0009f;        // 81*C2

    const f32x2 k1_ = K1, k2_ = K2;
    const f32x2 two_ = 2.0f, m2_ = -2.0f, e18_ = 18.0f, n9_ = 9.0f;
    const f32x2 mh_ = -0.5f, h_ = 0.5f, zero_ = 0.0f, one_ = 1.0f;
    const f32x2 a3_ = 0.85f / 3.0f, b3_ = 0.15f / 3.0f;

    __shared__ float tile[NPR * TW];   // 30720 B, plane-row pr = plane*INR + li
    __shared__ float hL[NPR];          // col c0b-1 per plane-row (reflected)
    __shared__ float hR[NPR];          // col c0b+TW per plane-row (reflected)

    const int tid  = threadIdx.x;                // 0..255
    const int lane = tid & 63;
    const int wv   = tid >> 6;                   // wave 0..3
    const int b    = blockIdx.z;
    const int c0b  = blockIdx.x * TW;
    const int rb   = blockIdx.y * TH - 1;        // global input row of li=0

    const size_t img = (size_t)IMG_H * IMG_W;
    const float* __restrict__ pl[NPL] = {
        pred + (size_t)b * CH * img,
        pred + (size_t)b * CH * img + img,
        pred + (size_t)b * CH * img + 2 * img,
        gt   + (size_t)b * CH * img,
        gt   + (size_t)b * CH * img + img,
        gt   + (size_t)b * CH * img + 2 * img };

    // ---- halo columns (VGPR roundtrip + ds_write; 120 of 256 threads) ----
    const int hcL = (c0b == 0) ? 1 : c0b - 1;                    // reflect(-1)=1
    const int hcR = (c0b + TW >= IMG_W) ? IMG_W - 2 : c0b + TW;  // reflect(1920)=1918
    if (tid < NPR) {
        const int p = tid / INR, li = tid % INR;
        const int r = reflect_row(rb + li);
        hL[tid] = pl[p][(size_t)r * IMG_W + hcL];
    } else if (tid >= 64 && tid < 64 + NPR) {
        const int pr = tid - 64;
        const int p = pr / INR, li = pr % INR;
        const int r = reflect_row(rb + li);
        hR[pr] = pl[p][(size_t)r * IMG_W + hcR];
    }

    // ---- main staging: 30 pair-instructions, 2 plane-rows (1 KiB) each ----
    // pair P covers pr = 2P (lanes 0-31) and 2P+1 (lanes 32-63);
    // pr = plane*INR + li with plane = P/5, li = 2*(P%5) + (lane>>5).
    const int npair = (wv < 3) ? 8 : 6;          // waves 0-2: P 0..23, wave 3: 24..29
    for (int k = 0; k < npair; ++k) {
        const int P  = 8 * wv + k;
        const int p  = P / 5;
        const int li = 2 * (P % 5) + (lane >> 5);
        const int r  = reflect_row(rb + li);
        const float* g = pl[p] + (size_t)r * IMG_W + c0b + (lane & 31) * 4;
        gload16(g, &tile[P * 256]);
    }
    __syncthreads();

    // ---- compute: thread = (row-pair rp = wave, col-pair cp = lane) ----
    const int cp = lane;                          // cols c0b+2cp, +2cp+1
    const int rp = wv;                            // out rows 2rp, 2rp+1 (block-rel)

    f32x2 Ax[CH], Ay[CH], Aw[CH], Ap[CH];   // input li 2rp..2rp+2 -> out 2rp
    f32x2 Bx[CH], By[CH], Bw[CH], Bp[CH];   // input li 2rp+1..2rp+3 -> out 2rp+1
    f32x2 l1r0 = zero_, l1r1 = zero_;

#define CONSUME(I, DOA, FIRSTA, DOB, FIRSTB, L1ACC)                         \
    _Pragma("unroll")                                                       \
    for (int c = 0; c < CH; ++c) {                                          \
        const int li_ = 2 * rp + (I);                                       \
        const int prx = c * INR + li_;                                      \
        const int pry = (c + CH) * INR + li_;                               \
        const f32x2 qxv = *reinterpret_cast<const f32x2*>(&tile[prx * TW + 2 * cp]); \
        const f32x2 qyv = *reinterpret_cast<const f32x2*>(&tile[pry * TW + 2 * cp]); \
        float xm = dpp_up1(qxv.y), ym = dpp_up1(qyv.y);                     \
        float xp = dpp_dn1(qxv.x), yp = dpp_dn1(qyv.x);                     \
        if (lane == 0)  { xm = hL[prx]; ym = hL[pry]; }                     \
        if (lane == 63) { xp = hR[prx]; yp = hR[pry]; }                     \
        if (DOB == false && DOA == false) {}                                \
        const f32x2 X0 = { xm, qxv.x }, X2 = { qxv.y, xp };                 \
        const f32x2 Y0 = { ym, qyv.x }, Y2 = { qyv.y, yp };                 \
        const f32x2 WX = X0 + qxv + X2;                                     \
        const f32x2 WY = Y0 + qyv + Y2;                                     \
        const f32x2 WP = FMA2(X2, Y2, FMA2(qxv, qyv, X0 * Y0));             \
        const f32x2 WW = FMA2(X2, X2, FMA2(Y2, Y2, FMA2(qxv, qxv,           \
                         FMA2(qyv, qyv, FMA2(X0, X0, Y0 * Y0)))));          \
        if (L1ACC) {                                                        \
            f32x2 d_ = qxv - qyv;                                           \
            d_.x = fabsf(d_.x); d_.y = fabsf(d_.y);                         \
            *(L1ACC) += d_;                                                 \
        }                                                                   \
        if (DOA) {                                                          \
            if (FIRSTA) { Ax[c] = WX; Ay[c] = WY; Aw[c] = WW; Ap[c] = WP; } \
            else        { Ax[c] += WX; Ay[c] += WY;                         \
                          Aw[c] += WW; Ap[c] += WP; }                       \
        }                                                                   \
        if (DOB) {                                                          \
            if (FIRSTB) { Bx[c] = WX; By[c] = WY; Bw[c] = WW; Bp[c] = WP; } \
            else        { Bx[c] += WX; By[c] += WY;                         \
                          Bw[c] += WW; Bp[c] += WP; }                       \
        }                                                                   \
    }

    CONSUME(0, true, true,  false, false, ((f32x2*)0))   // li 2rp   -> A
    CONSUME(1, true, false, true,  true,  (&l1r0))       // li 2rp+1 -> A,B ; L1 row0
    CONSUME(2, true, false, true,  false, (&l1r1))       // li 2rp+2 -> A,B ; L1 row1
    CONSUME(3, false, false, true, false, ((f32x2*)0))   // li 2rp+3 -> B
#undef CONSUME

    // ---- packed SSIM epilogue (moments scaled by 81; cancels in n/d) ----
#define SSIM2(AX, AY, AW, AP, ACC)                                          \
    {                                                                       \
        const f32x2 u  = (AX) * (AY);                                       \
        const f32x2 v  = FMA2((AY), (AY), (AX) * (AX));                     \
        const f32x2 n1 = FMA2(two_, u, k1_);                                \
        const f32x2 n2 = FMA2(e18_, (AP), FMA2(m2_, u, k2_));               \
        const f32x2 d1 = v + k1_;                                           \
        const f32x2 d2 = FMA2(n9_, (AW), k2_) - v;                          \
        const f32x2 nd = n1 * n2, dd = d1 * d2;                             \
        f32x2 rc;                                                           \
        rc.x = __builtin_amdgcn_rcpf(dd.x);                                 \
        rc.y = __builtin_amdgcn_rcpf(dd.y);                                 \
        f32x2 s = FMA2(mh_, nd * rc, h_);                                   \
        s = __builtin_elementwise_min(                                      \
                __builtin_elementwise_max(s, zero_), one_);                 \
        ACC = FMA2(a3_, s, ACC);                                            \
    }

    f32x2 o0 = b3_ * l1r0;
    f32x2 o1 = b3_ * l1r1;
#pragma unroll
    for (int c = 0; c < CH; ++c) {
        SSIM2(Ax[c], Ay[c], Aw[c], Ap[c], o0)
        SSIM2(Bx[c], By[c], Bw[c], Bp[c], o1)
    }
#undef SSIM2

    const int ro0 = blockIdx.y * TH + 2 * rp;
    float* op = out + ((size_t)b * IMG_H + ro0) * IMG_W + c0b + 2 * cp;
    *reinterpret_cast<f32x2*>(op) = o0;
    *reinterpret_cast<f32x2*>(op + IMG_W) = o1;
}

extern "C" void kernel_launch(void* const* d_in, const int* in_sizes, int n_in,
                              void* d_out, int out_size, void* d_ws, size_t ws_size,
                              hipStream_t stream) {
    const float* pred = (const float*)d_in[0];
    const float* gt   = (const float*)d_in[1];
    float* out = (float*)d_out;

    dim3 block(256, 1, 1);
    dim3 grid(IMG_W / TW, IMG_H / TH, 4);   // 15 x 135 x 4
    dssim_l1_kernel<<<grid, block, 0, stream>>>(pred, gt, out);
}

// Round 17
// 58.204 us; speedup vs baseline: 1.2333x; 1.2333x over previous
//
#include <hip/hip_runtime.h>

#define IMG_H 1080
#define IMG_W 1920
#define CH 3

typedef float f32x2 __attribute__((ext_vector_type(2)));

#if __has_builtin(__builtin_elementwise_fma)
#define FMA2(a, b, c) __builtin_elementwise_fma((a), (b), (c))
#else
#define FMA2(a, b, c) ((a) * (b) + (c))
#endif

__global__ __launch_bounds__(256)
void dssim_l1_kernel(const float* __restrict__ pred,
                     const float* __restrict__ gt,
                     float* __restrict__ out) {
    constexpr float K1 = 81.0f * 0.0001f;        // 81*C1
    constexpr float K2 = 81.0f * 0.0009f;        // 81*C2

    const f32x2 k1_ = K1, k2_ = K2;
    const f32x2 two_ = 2.0f, m2_ = -2.0f, e18_ = 18.0f, n9_ = 9.0f;
    const f32x2 mh_ = -0.5f, h_ = 0.5f, zero_ = 0.0f, one_ = 1.0f;
    const f32x2 a3_ = 0.85f / 3.0f, b3_ = 0.15f / 3.0f;

    const int lane = threadIdx.x;                // 0..63
    const int sl   = lane & 31;                  // lane in half-wave
    const int hh   = lane >> 5;                  // half 0/1
    const int wv   = threadIdx.y;                // 0..3
    const int b    = blockIdx.z;

    const int c0b  = blockIdx.x * 128;
    const int c0   = c0b + sl * 4;                       // 4 output cols c0..c0+3
    const int r    = blockIdx.y * 8 + wv * 2 + hh;       // ONE output row

    const int rows[3] = { (r == 0) ? 1 : r - 1, r,
                          (r == IMG_H - 1) ? IMG_H - 2 : r + 1 };

    const bool sl0 = (sl == 0), sl31 = (sl == 31);
    const bool is_edge = sl0 || sl31;
    const bool limg = sl0  && (blockIdx.x == 0);     // image left edge
    const bool rimg = sl31 && (blockIdx.x == 14);    // image right edge
    const int  hcol = sl0 ? max(c0 - 1, 0) : min(c0 + 4, IMG_W - 1);

    const size_t img = (size_t)IMG_H * IMG_W;
    const float* __restrict__ pb[2 * CH] = {
        pred + (size_t)b * CH * img,
        pred + (size_t)b * CH * img + img,
        pred + (size_t)b * CH * img + 2 * img,
        gt   + (size_t)b * CH * img,
        gt   + (size_t)b * CH * img + img,
        gt   + (size_t)b * CH * img + 2 * img };

    unsigned off[3];
#pragma unroll
    for (int i = 0; i < 3; ++i) off[i] = (unsigned)rows[i] * IMG_W;

    // ---- halo loads first (R11 lesson) ----
    float hxv[3][CH], hyv[3][CH];
    if (is_edge) {
#pragma unroll
        for (int i = 0; i < 3; ++i) {
            const unsigned ho = off[i] + (unsigned)hcol;
#pragma unroll
            for (int c = 0; c < CH; ++c) {
                hxv[i][c] = pb[c][ho];
                hyv[i][c] = pb[CH + c][ho];
            }
        }
    }

    // ---- 18 aligned float4 loads ----
    float4 qx[3][CH], qy[3][CH];
#pragma unroll
    for (int i = 0; i < 3; ++i) {
        const unsigned mo = off[i] + (unsigned)c0;
#pragma unroll
        for (int c = 0; c < CH; ++c) {
            qx[i][c] = *reinterpret_cast<const float4*>(pb[c]      + mo);
            qy[i][c] = *reinterpret_cast<const float4*>(pb[CH + c] + mo);
        }
    }

    // acc: pair L = output cols {c0,c0+1}, pair H = {c0+2,c0+3}
    f32x2 SxL[CH], SyL[CH], SwL[CH], SpL[CH];
    f32x2 SxH[CH], SyH[CH], SwH[CH], SpH[CH];
    f32x2 l1L = zero_, l1H = zero_;

#define CONSUME(I, FIRST, DOL1)                                             \
    _Pragma("unroll")                                                       \
    for (int c = 0; c < CH; ++c) {                                          \
        const float4 qxv = qx[I][c], qyv = qy[I][c];                        \
        float xm = __shfl_up(qxv.w, 1, 32),  ym = __shfl_up(qyv.w, 1, 32);  \
        float xp = __shfl_down(qxv.x, 1, 32), yp = __shfl_down(qyv.x, 1, 32);\
        if (sl0)  { xm = hxv[I][c]; ym = hyv[I][c]; }                       \
        if (sl31) { xp = hxv[I][c]; yp = hyv[I][c]; }                       \
        if (limg) { xm = qxv.y; ym = qyv.y; }      /* reflect(-1)=1 */      \
        if (rimg) { xp = qxv.z; yp = qyv.z; }      /* reflect(1920)=1918 */ \
        /* pair L taps */                                                   \
        const f32x2 T0L = { xm, qxv.x },    U0L = { ym, qyv.x };            \
        const f32x2 T1L = { qxv.x, qxv.y }, U1L = { qyv.x, qyv.y };         \
        const f32x2 T2L = { qxv.y, qxv.z }, U2L = { qyv.y, qyv.z };         \
        /* pair H taps */                                                   \
        const f32x2 T0H = { qxv.y, qxv.z }, U0H = { qyv.y, qyv.z };         \
        const f32x2 T1H = { qxv.z, qxv.w }, U1H = { qyv.z, qyv.w };         \
        const f32x2 T2H = { qxv.w, xp },    U2H = { qyv.w, yp };            \
        const f32x2 WXL = T0L + T1L + T2L, WYL = U0L + U1L + U2L;           \
        const f32x2 WPL = FMA2(T2L, U2L, FMA2(T1L, U1L, T0L * U0L));        \
        const f32x2 WWL = FMA2(T2L, T2L, FMA2(U2L, U2L, FMA2(T1L, T1L,      \
                          FMA2(U1L, U1L, FMA2(T0L, T0L, U0L * U0L)))));     \
        const f32x2 WXH = T0H + T1H + T2H, WYH = U0H + U1H + U2H;           \
        const f32x2 WPH = FMA2(T2H, U2H, FMA2(T1H, U1H, T0H * U0H));        \
        const f32x2 WWH = FMA2(T2H, T2H, FMA2(U2H, U2H, FMA2(T1H, T1H,      \
                          FMA2(U1H, U1H, FMA2(T0H, T0H, U0H * U0H)))));     \
        if (FIRST) {                                                        \
            SxL[c] = WXL; SyL[c] = WYL; SwL[c] = WWL; SpL[c] = WPL;         \
            SxH[c] = WXH; SyH[c] = WYH; SwH[c] = WWH; SpH[c] = WPH;         \
        } else {                                                            \
            SxL[c] += WXL; SyL[c] += WYL; SwL[c] += WWL; SpL[c] += WPL;     \
            SxH[c] += WXH; SyH[c] += WYH; SwH[c] += WWH; SpH[c] += WPH;     \
        }                                                                   \
        if (DOL1) {                                                         \
            f32x2 dL = T1L - U1L, dH = T1H - U1H;                           \
            dL.x = fabsf(dL.x); dL.y = fabsf(dL.y);                         \
            dH.x = fabsf(dH.x); dH.y = fabsf(dH.y);                         \
            l1L += dL; l1H += dH;                                           \
        }                                                                   \
    }

    CONSUME(0, true,  false)    // row r-1
    CONSUME(1, false, true)     // row r (centers {q.x,q.y} / {q.z,q.w} = T1L/T1H)
    CONSUME(2, false, false)    // row r+1
#undef CONSUME

    // ---- packed SSIM epilogue (moments scaled by 81; cancels in n/d) ----
#define SSIM2(AX, AY, AW, AP, ACC)                                          \
    {                                                                       \
        const f32x2 u  = (AX) * (AY);                                       \
        const f32x2 v  = FMA2((AY), (AY), (AX) * (AX));                     \
        const f32x2 n1 = FMA2(two_, u, k1_);                                \
        const f32x2 n2 = FMA2(e18_, (AP), FMA2(m2_, u, k2_));               \
        const f32x2 d1 = v + k1_;                                           \
        const f32x2 d2 = FMA2(n9_, (AW), k2_) - v;                          \
        const f32x2 nd = n1 * n2, dd = d1 * d2;                             \
        f32x2 rc;                                                           \
        rc.x = __builtin_amdgcn_rcpf(dd.x);                                 \
        rc.y = __builtin_amdgcn_rcpf(dd.y);                                 \
        f32x2 s = FMA2(mh_, nd * rc, h_);                                   \
        s = __builtin_elementwise_min(                                      \
                __builtin_elementwise_max(s, zero_), one_);                 \
        ACC = FMA2(a3_, s, ACC);                                            \
    }

    f32x2 oL = b3_ * l1L;
    f32x2 oH = b3_ * l1H;
#pragma unroll
    for (int c = 0; c < CH; ++c) {
        SSIM2(SxL[c], SyL[c], SwL[c], SpL[c], oL)
        SSIM2(SxH[c], SyH[c], SwH[c], SpH[c], oH)
    }
#undef SSIM2

    float4 o; o.x = oL.x; o.y = oL.y; o.z = oH.x; o.w = oH.y;
    *reinterpret_cast<float4*>(out + ((size_t)b * IMG_H + r) * IMG_W + c0) = o;
}

extern "C" void kernel_launch(void* const* d_in, const int* in_sizes, int n_in,
                              void* d_out, int out_size, void* d_ws, size_t ws_size,
                              hipStream_t stream) {
    const float* pred = (const float*)d_in[0];
    const float* gt   = (const float*)d_in[1];
    float* out = (float*)d_out;

    dim3 block(64, 4, 1);
    dim3 grid(IMG_W / 128, IMG_H / 8, 4);   // 15 x 135 x 4
    dssim_l1_kernel<<<grid, block, 0, stream>>>(pred, gt, out);
}

// Round 18
// 57.508 us; speedup vs baseline: 1.2482x; 1.0121x over previous
//
#include <hip/hip_runtime.h>

#define IMG_H 1080
#define IMG_W 1920
#define CH 3

typedef float f32x2 __attribute__((ext_vector_type(2)));

#if __has_builtin(__builtin_elementwise_fma)
#define FMA2(a, b, c) __builtin_elementwise_fma((a), (b), (c))
#else
#define FMA2(a, b, c) ((a) * (b) + (c))
#endif

// DPP wave shifts: single VALU op, no DS pipe, no lgkmcnt (validated R14).
__device__ __forceinline__ float dpp_up1(float x) {
    int i = __float_as_int(x);
    return __int_as_float(__builtin_amdgcn_update_dpp(i, i, 0x138, 0xF, 0xF, false));
}
__device__ __forceinline__ float dpp_dn1(float x) {
    int i = __float_as_int(x);
    return __int_as_float(__builtin_amdgcn_update_dpp(i, i, 0x130, 0xF, 0xF, false));
}

__global__ __launch_bounds__(256)
void dssim_l1_kernel(const float* __restrict__ pred,
                     const float* __restrict__ gt,
                     float* __restrict__ out) {
    constexpr float K1 = 81.0f * 0.0001f;        // 81*C1
    constexpr float K2 = 81.0f * 0.0009f;        // 81*C2

    const f32x2 k1_ = K1, k2_ = K2;
    const f32x2 two_ = 2.0f, m2_ = -2.0f, e18_ = 18.0f, n9_ = 9.0f;
    const f32x2 mh_ = -0.5f, h_ = 0.5f, zero_ = 0.0f, one_ = 1.0f;
    const f32x2 a3_ = 0.85f / 3.0f, b3_ = 0.15f / 3.0f;

    const int lane = threadIdx.x;                               // 0..63
    const int r0   = (blockIdx.y * 4 + threadIdx.y) * 2;        // even output row
    const int b    = blockIdx.z;
    const int c0   = blockIdx.x * 128 + 2 * lane;               // 2 output cols

    // input rows r0-1 .. r0+2 with reflection
    const int rws[4] = { (r0 == 0) ? 1 : r0 - 1,
                         r0, r0 + 1,
                         (r0 + 2 == IMG_H) ? IMG_H - 2 : r0 + 2 };

    const bool l0 = (lane == 0), l63 = (lane == 63);
    const bool limg = l0  && (blockIdx.x == 0);    // image left edge lane
    const bool rimg = l63 && (blockIdx.x == 14);   // image right edge lane
    const int  hcol = l0 ? max(c0 - 1, 0) : min(c0 + 2, IMG_W - 1);
    const bool is_edge = l0 || l63;

    const size_t img = (size_t)IMG_H * IMG_W;
    const float* __restrict__ pb[2 * CH] = {
        pred + (size_t)b * CH * img,
        pred + (size_t)b * CH * img + img,
        pred + (size_t)b * CH * img + 2 * img,
        gt   + (size_t)b * CH * img,
        gt   + (size_t)b * CH * img + img,
        gt   + (size_t)b * CH * img + 2 * img };

    // shared 32-bit voffsets (one per input row, reused across all 6 planes)
    unsigned off[4];
#pragma unroll
    for (int i = 0; i < 4; ++i) off[i] = (unsigned)rws[i] * IMG_W + (unsigned)c0;

    // ---- halo loads first (R11 lesson: last-issued halo forces full drain) ----
    float hx[4][CH], hy[4][CH];
    if (is_edge) {
        const unsigned hbase = (unsigned)hcol - (unsigned)c0;  // constant delta
#pragma unroll
        for (int i = 0; i < 4; ++i) {
            const unsigned ho = off[i] + hbase;
#pragma unroll
            for (int c = 0; c < CH; ++c) {
                hx[i][c] = pb[c][ho];
                hy[i][c] = pb[CH + c][ho];
            }
        }
    }

    // ---- main 24 packed-pair loads ----
    f32x2 qx[4][CH], qy[4][CH];
#pragma unroll
    for (int i = 0; i < 4; ++i) {
#pragma unroll
        for (int c = 0; c < CH; ++c) {
            qx[i][c] = *reinterpret_cast<const f32x2*>(pb[c]      + off[i]);
            qy[i][c] = *reinterpret_cast<const f32x2*>(pb[CH + c] + off[i]);
        }
    }

    // window accumulators, packed over the 2 output columns
    f32x2 Ax[CH], Ay[CH], Aw[CH], Ap[CH];   // rows -1,0,1 -> out r0
    f32x2 Bx[CH], By[CH], Bw[CH], Bp[CH];   // rows 0,1,2  -> out r0+1

#define CONSUME(I, DOA, FIRSTA, DOB, FIRSTB)                                \
    _Pragma("unroll")                                                       \
    for (int c = 0; c < CH; ++c) {                                          \
        const f32x2 qxv = qx[I][c], qyv = qy[I][c];                         \
        float xm = dpp_up1(qxv.y), ym = dpp_up1(qyv.y);                     \
        float xp = dpp_dn1(qxv.x), yp = dpp_dn1(qyv.x);                     \
        if (l0)   { xm = hx[I][c]; ym = hy[I][c]; }                         \
        if (l63)  { xp = hx[I][c]; yp = hy[I][c]; }                         \
        if (limg) { xm = qxv.y; ym = qyv.y; }      /* reflect(-1)=1 */      \
        if (rimg) { xp = qxv.x; yp = qyv.x; }      /* reflect(1920)=1918 */ \
        const f32x2 X0 = { xm, qxv.x }, X2 = { qxv.y, xp };                 \
        const f32x2 Y0 = { ym, qyv.x }, Y2 = { qyv.y, yp };                 \
        const f32x2 WX = X0 + qxv + X2;                                     \
        const f32x2 WY = Y0 + qyv + Y2;                                     \
        const f32x2 WP = FMA2(X2, Y2, FMA2(qxv, qyv, X0 * Y0));             \
        const f32x2 WW = FMA2(X2, X2, FMA2(Y2, Y2, FMA2(qxv, qxv,           \
                         FMA2(qyv, qyv, FMA2(X0, X0, Y0 * Y0)))));          \
        if (DOA) {                                                          \
            if (FIRSTA) { Ax[c] = WX; Ay[c] = WY; Aw[c] = WW; Ap[c] = WP; } \
            else        { Ax[c] += WX; Ay[c] += WY;                         \
                          Aw[c] += WW; Ap[c] += WP; }                       \
        }                                                                   \
        if (DOB) {                                                          \
            if (FIRSTB) { Bx[c] = WX; By[c] = WY; Bw[c] = WW; Bp[c] = WP; } \
            else        { Bx[c] += WX; By[c] += WY;                         \
                          Bw[c] += WW; Bp[c] += WP; }                       \
        }                                                                   \
    }

    CONSUME(0, true, true,  false, false)   // row r0-1 -> A
    CONSUME(1, true, false, true,  true)    // row r0   -> A, B
    CONSUME(2, true, false, true,  false)   // row r0+1 -> A, B
    CONSUME(3, false, false, true, false)   // row r0+2 -> B
#undef CONSUME

    // L1 terms from raw center rows (row idx 1 -> out r0, idx 2 -> out r0+1)
    f32x2 l1r0 = zero_, l1r1 = zero_;
#pragma unroll
    for (int c = 0; c < CH; ++c) {
#if __has_builtin(__builtin_elementwise_abs)
        l1r0 += __builtin_elementwise_abs(qx[1][c] - qy[1][c]);
        l1r1 += __builtin_elementwise_abs(qx[2][c] - qy[2][c]);
#else
        f32x2 d0 = qx[1][c] - qy[1][c], d1 = qx[2][c] - qy[2][c];
        d0.x = fabsf(d0.x); d0.y = fabsf(d0.y);
        d1.x = fabsf(d1.x); d1.y = fabsf(d1.y);
        l1r0 += d0; l1r1 += d1;
#endif
    }

    // ---- packed SSIM epilogue (moments scaled by 81; cancels in n/d) ----
#define SSIM2(AX, AY, AW, AP, ACC)                                          \
    {                                                                       \
        const f32x2 u  = (AX) * (AY);                                       \
        const f32x2 v  = FMA2((AY), (AY), (AX) * (AX));                     \
        const f32x2 n1 = FMA2(two_, u, k1_);                                \
        const f32x2 n2 = FMA2(e18_, (AP), FMA2(m2_, u, k2_));               \
        const f32x2 d1 = v + k1_;                                           \
        const f32x2 d2 = FMA2(n9_, (AW), k2_) - v;                          \
        const f32x2 nd = n1 * n2, dd = d1 * d2;                             \
        f32x2 rc;                                                           \
        rc.x = __builtin_amdgcn_rcpf(dd.x);                                 \
        rc.y = __builtin_amdgcn_rcpf(dd.y);                                 \
        f32x2 s = FMA2(mh_, nd * rc, h_);                                   \
        s = __builtin_elementwise_min(                                      \
                __builtin_elementwise_max(s, zero_), one_);                 \
        ACC = FMA2(a3_, s, ACC);                                            \
    }

    f32x2 o0 = b3_ * l1r0;
    f32x2 o1 = b3_ * l1r1;
#pragma unroll
    for (int c = 0; c < CH; ++c) {
        SSIM2(Ax[c], Ay[c], Aw[c], Ap[c], o0)
        SSIM2(Bx[c], By[c], Bw[c], Bp[c], o1)
    }
#undef SSIM2

    // nontemporal stores: output is write-once/never-read — keep it out of
    // L2/L3 so the 199 MB input set stays L3-resident across graph replays.
    float* op = out + ((size_t)b * IMG_H + r0) * IMG_W + c0;
    __builtin_nontemporal_store(o0, reinterpret_cast<f32x2*>(op));
    __builtin_nontemporal_store(o1, reinterpret_cast<f32x2*>(op + IMG_W));
}

extern "C" void kernel_launch(void* const* d_in, const int* in_sizes, int n_in,
                              void* d_out, int out_size, void* d_ws, size_t ws_size,
                              hipStream_t stream) {
    const float* pred = (const float*)d_in[0];
    const float* gt   = (const float*)d_in[1];
    float* out = (float*)d_out;

    dim3 block(64, 4, 1);
    dim3 grid(IMG_W / 128, IMG_H / 8, 4);   // 15 x 135 x 4
    dssim_l1_kernel<<<grid, block, 0, stream>>>(pred, gt, out);
}